// Round 12
// baseline (2174.811 us; speedup 1.0000x reference)
//
#include <hip/hip_runtime.h>
#include <hip/hip_bf16.h>

// Problem constants: B=32, T=1024, D=512, K=3, L=max_len=4096.
// *** ABLATION ROUND: five reps-amplified variants of the GEMM K-loop, each
// deleting one pipe (DCE-guarded), dispatched before the real chain so they
// occupy rocprof's top-5. Output is still correct (variants write dead
// scratch; real round-9 kernels run after). Per-variant per-rep cost =
// dur_us/reps decomposes the 4250 cyc/step budget empirically. ***
#define BB 32
#define TT 1024
#define DD 512
#define LL 4096
#define KDIM 1536
#define TP 1026
#define ROWS (BB * TT)
#define NT (KDIM / 32)   // 48 K-steps

typedef __attribute__((ext_vector_type(8))) short short8;
typedef __attribute__((ext_vector_type(8))) unsigned short ushort8;
typedef __attribute__((ext_vector_type(4))) float floatx4;
typedef __attribute__((ext_vector_type(4))) int intx4;

__device__ __forceinline__ unsigned short f2bf(float f) {
  unsigned int u = __builtin_bit_cast(unsigned int, f);
  u += 0x7FFF + ((u >> 16) & 1);
  return (unsigned short)(u >> 16);
}

__device__ __forceinline__ void keep8(const short8& x) {
  intx4 t = __builtin_bit_cast(intx4, x);
  asm volatile("" ::"v"(t[0]), "v"(t[1]), "v"(t[2]), "v"(t[3]));
}

#define GLOAD_LDS16(g, l)                                          \
  __builtin_amdgcn_global_load_lds(                                \
      (const __attribute__((address_space(1))) void*)(g),          \
      (__attribute__((address_space(3))) void*)(l), 16, 0, 0)

// ---------------------------------------------------------------------------
// Merged prep kernel (unchanged from round 9).
// ---------------------------------------------------------------------------
#define PAD_BLKS ((BB * TP) / 4)
#define W0 (PAD_BLKS + 16)
#define C0 (W0 + 384)
#define PREP_BLKS (C0 + 32)

__global__ __launch_bounds__(256) void prep_kernel(
    const float* __restrict__ X, unsigned short* __restrict__ Xp,
    unsigned short* __restrict__ Hp,
    const float* __restrict__ W1, unsigned short* __restrict__ Wt1,
    const float* __restrict__ W2, unsigned short* __restrict__ Wt2,
    const int* __restrict__ dur, int* __restrict__ cum,
    int* __restrict__ idx) {
  __shared__ float tile[64][65];
  const int tid = threadIdx.x;
  const int lane = tid & 63;

  if (blockIdx.x >= C0) {
    int* ls = reinterpret_cast<int*>(tile);
    const int b = blockIdx.x - C0;
    int4 v = reinterpret_cast<const int4*>(dur + b * TT)[tid];
    const int s0 = v.x, s1 = s0 + v.y, s2 = s1 + v.z, s3 = s2 + v.w;
    ls[tid] = s3;
    __syncthreads();
    for (int off = 1; off < 256; off <<= 1) {
      int x = (tid >= off) ? ls[tid - off] : 0;
      __syncthreads();
      ls[tid] += x;
      __syncthreads();
    }
    const int base = tid ? ls[tid - 1] : 0;
    int4 o = {base + s0, base + s1, base + s2, base + s3};
    reinterpret_cast<int4*>(cum + b * TT)[tid] = o;
    int* ib = idx + b * LL;
    int st = base;
    const int dv[4] = {v.x, v.y, v.z, v.w};
#pragma unroll
    for (int k = 0; k < 4; ++k) {
      const int e = min(st + dv[k], LL);
      for (int j = st; j < e; ++j) ib[j] = 4 * tid + k;
      st += dv[k];
    }
    return;
  }
  if (blockIdx.x >= W0) {
    const int w = blockIdx.x - W0;
    const int z = w / 192;
    const int rem = w - z * 192;
    const int bx = rem & 7;
    const int by = rem >> 3;
    const float* W = z ? W2 : W1;
    unsigned short* Wt = z ? Wt2 : Wt1;
    const int n0 = bx * 64;
    const int k0 = by * 64;
    const int c = lane;
    const int r4 = tid >> 6;
#pragma unroll
    for (int r = 0; r < 16; ++r)
      tile[r * 4 + r4][c] = W[(long)(k0 + r * 4 + r4) * DD + n0 + c];
    __syncthreads();
#pragma unroll
    for (int r = 0; r < 16; ++r)
      Wt[(long)(n0 + r * 4 + r4) * KDIM + k0 + c] = f2bf(tile[c][r * 4 + r4]);
    return;
  }
  if (blockIdx.x >= PAD_BLKS) {
    const int hid = (blockIdx.x - PAD_BLKS) * 4 + (tid >> 6);
    const int b = hid >> 1;
    const long r = (long)b * TP + ((hid & 1) ? (TP - 1) : 0);
    *reinterpret_cast<ushort8*>(Hp + r * DD + lane * 8) = (ushort8)0;
    return;
  }
  const int row = blockIdx.x * 4 + (tid >> 6);
  const int b  = row / TP;
  const int pr = row - b * TP;
  ushort8* o = reinterpret_cast<ushort8*>(Xp + (long)row * DD + lane * 8);
  ushort8 v;
  if (pr == 0 || pr == TP - 1) {
    v = (ushort8)0;
  } else {
    const float* p = X + ((long)(b * TT + pr - 1)) * DD + lane * 8;
    float4 a = *reinterpret_cast<const float4*>(p);
    float4 c = *reinterpret_cast<const float4*>(p + 4);
    v[0] = f2bf(a.x); v[1] = f2bf(a.y); v[2] = f2bf(a.z); v[3] = f2bf(a.w);
    v[4] = f2bf(c.x); v[5] = f2bf(c.y); v[6] = f2bf(c.z); v[7] = f2bf(c.w);
  }
  *o = v;
}

// ---------------------------------------------------------------------------
// ABLATION kernel: round-9 GEMM geometry (16 waves 2Mx8N, acc[4][4], 3-buf,
// counted vmcnt(3)/(2)), with one pipe deleted per variant:
//   V0: full            (stage + ds_read + MFMA + barrier)   reps=8
//   V1: no MFMA         (loads kept live via asm)            reps=8
//   V2: no ds_read      (MFMA from register fragments)       reps=8
//   V3: no staging      (single pre-staged buffer)           reps=8
//   V4: MFMA+barrier    (no memory at all)                   reps=16
// Writes acc-sum to dead scratch (keeps everything live; gather overwrites).
// ---------------------------------------------------------------------------
template <int V>
__global__ __launch_bounds__(1024, 4) void ablate_kernel(
    const unsigned short* __restrict__ Xp, const unsigned short* __restrict__ Wt,
    float* __restrict__ scr, int reps) {
  __shared__ unsigned short As[3][128 * 32];
  __shared__ unsigned short Bs[3][512 * 32];

  const int tid  = threadIdx.x;
  const int lane = tid & 63;
  const int wid  = tid >> 6;
  const int srow = lane >> 2;
  const int gchunk = (lane & 3) ^ (srow & 3) ^ ((srow >> 2) & 3);
  const int frow = lane & 15;
  const int quad = lane >> 4;
  const int rdch = quad ^ (frow & 3) ^ ((frow >> 2) & 3);
  const int wm = (wid >> 3) * 64;
  const int wn = (wid & 7) * 64;
  const int m0 = blockIdx.x * 128;
  const int bA = m0 >> 10;
  const int t0 = m0 & (TT - 1);

  const unsigned short* gA0 =
      Xp + (long)(bA * TP + t0 + (wid & 7) * 16 + srow) * DD + gchunk * 8;
  const int bb0 = (wid < 8) ? wid * 32 : 256 + (wid - 8) * 32;
  const unsigned short* gB0 =
      Wt + (long)(bb0 + srow) * KDIM + gchunk * 8;

  floatx4 acc[4][4];
#pragma unroll
  for (int i = 0; i < 4; ++i)
#pragma unroll
    for (int j = 0; j < 4; ++j) acc[i][j] = (floatx4){0.f, 0.f, 0.f, 0.f};

  // Register fragments for V2/V4 (VALU-initialized -> live in VGPRs).
  short8 xf, yf;
#pragma unroll
  for (int j = 0; j < 8; ++j) {
    xf[j] = (short)(tid * 8 + j);
    yf[j] = (short)(tid * 8 + j + 3);
  }

#define STAGE(bi, kk)                                                         \
  do {                                                                        \
    const int tap_ = (kk) >> 9;                                               \
    const int c0_  = (kk) & 511;                                              \
    if (wid < 8)                                                              \
      GLOAD_LDS16(gA0 + (long)tap_ * DD + c0_, &As[bi][(wid * 16) * 32]);     \
    GLOAD_LDS16(gB0 + (kk),                &Bs[bi][bb0 * 32]);                \
    GLOAD_LDS16(gB0 + (long)16 * KDIM + (kk), &Bs[bi][(bb0 + 16) * 32]);      \
  } while (0)

#define STEPBODY(rb)                                                          \
  do {                                                                        \
    if (V == 0 || V == 1 || V == 3) {                                         \
      short8 a_[4], b_[4];                                                    \
      _Pragma("unroll")                                                       \
      for (int i = 0; i < 4; ++i)                                             \
        a_[i] = *reinterpret_cast<const short8*>(                             \
            &As[rb][(wm + i * 16 + frow) * 32 + rdch * 8]);                   \
      _Pragma("unroll")                                                       \
      for (int j = 0; j < 4; ++j)                                             \
        b_[j] = *reinterpret_cast<const short8*>(                             \
            &Bs[rb][(wn + j * 16 + frow) * 32 + rdch * 8]);                   \
      if (V == 1) {                                                           \
        _Pragma("unroll")                                                     \
        for (int i = 0; i < 4; ++i) keep8(a_[i]);                             \
        _Pragma("unroll")                                                     \
        for (int j = 0; j < 4; ++j) keep8(b_[j]);                             \
      } else {                                                                \
        _Pragma("unroll")                                                     \
        for (int i = 0; i < 4; ++i)                                           \
          _Pragma("unroll")                                                   \
          for (int j = 0; j < 4; ++j)                                         \
            acc[i][j] = __builtin_amdgcn_mfma_f32_16x16x32_bf16(              \
                a_[i], b_[j], acc[i][j], 0, 0, 0);                            \
      }                                                                       \
    } else { /* V2, V4: MFMA from registers */                                \
      _Pragma("unroll")                                                       \
      for (int i = 0; i < 4; ++i)                                             \
        _Pragma("unroll")                                                     \
        for (int j = 0; j < 4; ++j)                                           \
          acc[i][j] = __builtin_amdgcn_mfma_f32_16x16x32_bf16(                \
              xf, yf, acc[i][j], 0, 0, 0);                                    \
    }                                                                         \
  } while (0)

  if (V == 3) {  // one-time stage of buffer 0
    STAGE(0, 0);
    asm volatile("s_waitcnt vmcnt(0)" ::: "memory");
    __syncthreads();
  }

  for (int rp = 0; rp < reps; ++rp) {
    if (V <= 2) { STAGE(0, 0); STAGE(1, 32); }
    int cur = 0, stg = 2;
    for (int t = 0; t < NT - 1; ++t) {
      if (V <= 2) {
        if (wid < 8) asm volatile("s_waitcnt vmcnt(3)" ::: "memory");
        else         asm volatile("s_waitcnt vmcnt(2)" ::: "memory");
      }
      __builtin_amdgcn_s_barrier();
      __builtin_amdgcn_sched_barrier(0);
      if (V <= 2) { if (t + 2 < NT) STAGE(stg, (t + 2) * 32); }
      STEPBODY((V == 3) ? 0 : cur);
      cur = (cur == 2) ? 0 : cur + 1;
      stg = (stg == 2) ? 0 : stg + 1;
    }
    if (V <= 2) asm volatile("s_waitcnt vmcnt(0)" ::: "memory");
    __builtin_amdgcn_s_barrier();
    __builtin_amdgcn_sched_barrier(0);
    STEPBODY((V == 3) ? 0 : cur);
    __syncthreads();  // rep boundary quiesce
  }
#undef STEPBODY
#undef STAGE

  float s = 0.f;
#pragma unroll
  for (int i = 0; i < 4; ++i)
#pragma unroll
    for (int j = 0; j < 4; ++j)
#pragma unroll
      for (int r = 0; r < 4; ++r) s += acc[i][j][r];
  scr[(long)blockIdx.x * 1024 + tid] = s;
}

// ---------------------------------------------------------------------------
// Production fused conv+LN kernel — round-9 form, verbatim (best: 512.5 us).
// ---------------------------------------------------------------------------
template <int LAYER>
__global__ __launch_bounds__(1024, 4) void fused_conv_ln_kernel(
    const unsigned short* __restrict__ Xp, const unsigned short* __restrict__ Wt,
    const float* __restrict__ bias, const float* __restrict__ g,
    const float* __restrict__ be, const float* __restrict__ lw,
    const float* __restrict__ lb, unsigned short* __restrict__ Hp,
    float* __restrict__ dpo) {
  __shared__ unsigned short As[3][128 * 32];
  __shared__ unsigned short Bs[3][512 * 32];
  __shared__ float sS[8][128];
  __shared__ float sQ[8][128];
  __shared__ float muL[128];
  __shared__ float rsL[128];

  const int tid  = threadIdx.x;
  const int lane = tid & 63;
  const int wid  = tid >> 6;
  const int srow = lane >> 2;
  const int gchunk = (lane & 3) ^ (srow & 3) ^ ((srow >> 2) & 3);
  const int frow = lane & 15;
  const int quad = lane >> 4;
  const int rdch = quad ^ (frow & 3) ^ ((frow >> 2) & 3);
  const int wm = (wid >> 3) * 64;
  const int wn = (wid & 7) * 64;
  const int wc = wid & 7;

  const int m0 = blockIdx.x * 128;
  const int bA = m0 >> 10;
  const int t0 = m0 & (TT - 1);

  const unsigned short* gA0 =
      Xp + (long)(bA * TP + t0 + (wid & 7) * 16 + srow) * DD + gchunk * 8;
  const int bb0 = (wid < 8) ? wid * 32 : 256 + (wid - 8) * 32;
  const unsigned short* gB0 =
      Wt + (long)(bb0 + srow) * KDIM + gchunk * 8;

  floatx4 acc[4][4];
#pragma unroll
  for (int i = 0; i < 4; ++i)
#pragma unroll
    for (int j = 0; j < 4; ++j) acc[i][j] = (floatx4){0.f, 0.f, 0.f, 0.f};

#define STAGE(bi, kk)                                                         \
  do {                                                                        \
    const int tap_ = (kk) >> 9;                                               \
    const int c0_  = (kk) & 511;                                              \
    if (wid < 8)                                                              \
      GLOAD_LDS16(gA0 + (long)tap_ * DD + c0_, &As[bi][(wid * 16) * 32]);     \
    GLOAD_LDS16(gB0 + (kk),                &Bs[bi][bb0 * 32]);                \
    GLOAD_LDS16(gB0 + (long)16 * KDIM + (kk), &Bs[bi][(bb0 + 16) * 32]);      \
  } while (0)

#define COMPUTE(bi)                                                           \
  do {                                                                        \
    short8 a_[4], b_[4];                                                      \
    _Pragma("unroll")                                                         \
    for (int i = 0; i < 4; ++i)                                               \
      a_[i] = *reinterpret_cast<const short8*>(                               \
          &As[bi][(wm + i * 16 + frow) * 32 + rdch * 8]);                     \
    _Pragma("unroll")                                                         \
    for (int j = 0; j < 4; ++j)                                               \
      b_[j] = *reinterpret_cast<const short8*>(                               \
          &Bs[bi][(wn + j * 16 + frow) * 32 + rdch * 8]);                     \
    _Pragma("unroll")                                                         \
    for (int i = 0; i < 4; ++i)                                               \
      _Pragma("unroll")                                                       \
      for (int j = 0; j < 4; ++j)                                             \
        acc[i][j] = __builtin_amdgcn_mfma_f32_16x16x32_bf16(                  \
            a_[i], b_[j], acc[i][j], 0, 0, 0);                                \
  } while (0)

  STAGE(0, 0);
  STAGE(1, 32);

  int cur = 0;
  int stg = 2;
  for (int t = 0; t < NT - 1; ++t) {
    if (wid < 8) asm volatile("s_waitcnt vmcnt(3)" ::: "memory");
    else         asm volatile("s_waitcnt vmcnt(2)" ::: "memory");
    __builtin_amdgcn_s_barrier();
    __builtin_amdgcn_sched_barrier(0);
    if (t + 2 < NT) STAGE(stg, (t + 2) * 32);
    COMPUTE(cur);
    cur = (cur == 2) ? 0 : cur + 1;
    stg = (stg == 2) ? 0 : stg + 1;
  }
  asm volatile("s_waitcnt vmcnt(0)" ::: "memory");
  __builtin_amdgcn_s_barrier();
  __builtin_amdgcn_sched_barrier(0);
  COMPUTE(cur);
#undef STAGE
#undef COMPUTE

  float bz[4];
#pragma unroll
  for (int j = 0; j < 4; ++j) bz[j] = bias[wn + j * 16 + frow];
#pragma unroll
  for (int i = 0; i < 4; ++i)
#pragma unroll
    for (int j = 0; j < 4; ++j)
#pragma unroll
      for (int r = 0; r < 4; ++r)
        acc[i][j][r] = fmaxf(acc[i][j][r] + bz[j], 0.f);

  float ps[16], pq[16];
#pragma unroll
  for (int i = 0; i < 4; ++i)
#pragma unroll
    for (int r = 0; r < 4; ++r) {
      float s = 0.f, q = 0.f;
#pragma unroll
      for (int j = 0; j < 4; ++j) {
        const float v = acc[i][j][r];
        s += v; q += v * v;
      }
      ps[i * 4 + r] = s; pq[i * 4 + r] = q;
    }
#pragma unroll
  for (int off = 1; off < 16; off <<= 1)
#pragma unroll
    for (int k = 0; k < 16; ++k) {
      ps[k] += __shfl_xor(ps[k], off);
      pq[k] += __shfl_xor(pq[k], off);
    }
  if (frow == 0) {
#pragma unroll
    for (int i = 0; i < 4; ++i)
#pragma unroll
      for (int r = 0; r < 4; ++r) {
        const int row = wm + i * 16 + quad * 4 + r;
        sS[wc][row] = ps[i * 4 + r];
        sQ[wc][row] = pq[i * 4 + r];
      }
  }
  __syncthreads();
  if (tid < 128) {
    float s = 0.f, q = 0.f;
#pragma unroll
    for (int c = 0; c < 8; ++c) { s += sS[c][tid]; q += sQ[c][tid]; }
    const float mu = s * (1.f / DD);
    const float var = q * (1.f / DD) - mu * mu;
    muL[tid] = mu;
    rsL[tid] = rsqrtf(var + 1e-5f);
  }
  __syncthreads();

  float gg[4], bb[4];
#pragma unroll
  for (int j = 0; j < 4; ++j) {
    gg[j] = g[wn + j * 16 + frow];
    bb[j] = be[wn + j * 16 + frow];
  }

  if constexpr (LAYER == 1) {
    unsigned short* Ls = reinterpret_cast<unsigned short*>(&Bs[0][0]);
    const int h = wm >> 6;
#pragma unroll
    for (int ph = 0; ph < 2; ++ph) {
      __syncthreads();
      if (h == ph) {
#pragma unroll
        for (int i = 0; i < 4; ++i)
#pragma unroll
          for (int r = 0; r < 4; ++r) {
            const int row = wm + i * 16 + quad * 4 + r;
            const float mu = muL[row];
            const float rs = rsL[row];
            const int lrow = row - ph * 64;
#pragma unroll
            for (int j = 0; j < 4; ++j) {
              const float v = (acc[i][j][r] - mu) * rs * gg[j] + bb[j];
              Ls[lrow * 520 + wn + j * 16 + frow] = f2bf(v);
            }
          }
      }
      __syncthreads();
      const long gbase = (long)(bA * TP + t0 + ph * 64 + 1) * DD;
#pragma unroll
      for (int it = 0; it < 4; ++it) {
        const int r2 = it * 16 + wid;
        const int cc = lane * 8;
        ushort8 val = *reinterpret_cast<const ushort8*>(&Ls[r2 * 520 + cc]);
        *reinterpret_cast<ushort8*>(&Hp[gbase + (long)r2 * DD + cc]) = val;
      }
    }
  } else {
    float ww[4];
#pragma unroll
    for (int j = 0; j < 4; ++j) ww[j] = lw[wn + j * 16 + frow];
#pragma unroll
    for (int i = 0; i < 4; ++i)
#pragma unroll
      for (int r = 0; r < 4; ++r) {
        const int row = wm + i * 16 + quad * 4 + r;
        const float mu = muL[row];
        const float rs = rsL[row];
        float d = 0.f;
#pragma unroll
        for (int j = 0; j < 4; ++j) {
          const float v = (acc[i][j][r] - mu) * rs * gg[j] + bb[j];
          d += v * ww[j];
        }
#pragma unroll
        for (int off = 1; off < 16; off <<= 1) d += __shfl_xor(d, off);
        if (frow == 0) sS[wc][row] = d;
      }
    __syncthreads();
    if (tid < 128) {
      float s = lb[0];
#pragma unroll
      for (int c = 0; c < 8; ++c) s += sS[c][tid];
      dpo[blockIdx.x * 128 + tid] = s;
    }
  }
}

// ---------------------------------------------------------------------------
// Gather/expand (round-9 form).
// ---------------------------------------------------------------------------
__global__ __launch_bounds__(512) void gather_kernel(
    const float* __restrict__ X, const int* __restrict__ cum,
    const int* __restrict__ idx, float* __restrict__ out) {
  const long gf = (long)blockIdx.x * 4 + (threadIdx.x >> 7);
  const int tl = threadIdx.x & 127;
  const int b = (int)(gf >> 12);
  const int j = (int)(gf & (LL - 1));
  const int total = cum[b * TT + TT - 1];
  floatx4* o = reinterpret_cast<floatx4*>(out + gf * DD) + tl;
  if (j >= total) {
    *o = (floatx4){0.f, 0.f, 0.f, 0.f};
    return;
  }
  const int lo = idx[b * LL + j];
  const floatx4* src =
      reinterpret_cast<const floatx4*>(X + ((long)b * TT + lo) * DD) + tl;
  *o = *src;
}

// ---------------------------------------------------------------------------
extern "C" void kernel_launch(void* const* d_in, const int* in_sizes, int n_in,
                              void* d_out, int out_size, void* d_ws,
                              size_t ws_size, hipStream_t stream) {
  const float* enc = (const float*)d_in[0];
  const int* dur   = (const int*)d_in[1];
  const float* w1  = (const float*)d_in[2];
  const float* b1  = (const float*)d_in[3];
  const float* g1  = (const float*)d_in[4];
  const float* be1 = (const float*)d_in[5];
  const float* w2  = (const float*)d_in[6];
  const float* b2  = (const float*)d_in[7];
  const float* g2  = (const float*)d_in[8];
  const float* be2 = (const float*)d_in[9];
  const float* lw  = (const float*)d_in[10];
  const float* lb  = (const float*)d_in[11];

  float* out = (float*)d_out;
  float* expanded = out;
  float* dpo = out + (long)BB * LL * DD;

  unsigned short* enc_pad = (unsigned short*)(expanded);              // 33.6 MB
  unsigned short* h1_pad  = (unsigned short*)(expanded + 9000000);    // 33.6 MB
  unsigned short* wt1     = (unsigned short*)(expanded + 18000000);   // 1.5 MB
  unsigned short* wt2     = (unsigned short*)(expanded + 18400000);   // 1.5 MB
  float* scr = expanded + 30000000;  // 1 MB dead scratch (gather overwrites)
  int* cum = (int*)d_ws;
  int* idx = (int*)d_ws + ROWS;

  prep_kernel<<<PREP_BLKS, 256, 0, stream>>>(enc, enc_pad, h1_pad, w1, wt1,
                                             w2, wt2, dur, cum, idx);

  // --- ablation dispatches (dead scratch output; top-5 occupants) ---
  ablate_kernel<0><<<ROWS / 128, 1024, 0, stream>>>(enc_pad, wt1, scr, 8);
  ablate_kernel<1><<<ROWS / 128, 1024, 0, stream>>>(enc_pad, wt1, scr, 8);
  ablate_kernel<2><<<ROWS / 128, 1024, 0, stream>>>(enc_pad, wt1, scr, 8);
  ablate_kernel<3><<<ROWS / 128, 1024, 0, stream>>>(enc_pad, wt1, scr, 8);
  ablate_kernel<4><<<ROWS / 128, 1024, 0, stream>>>(enc_pad, wt1, scr, 16);

  // --- production chain (round-9 form) ---
  fused_conv_ln_kernel<1><<<ROWS / 128, 1024, 0, stream>>>(
      enc_pad, wt1, b1, g1, be1, nullptr, nullptr, h1_pad, nullptr);
  fused_conv_ln_kernel<2><<<ROWS / 128, 1024, 0, stream>>>(
      h1_pad, wt2, b2, g2, be2, lw, lb, nullptr, dpo);

  gather_kernel<<<BB * LL / 4, 512, 0, stream>>>(enc, cum, idx, expanded);
}

// Round 13
// 505.784 us; speedup vs baseline: 4.2999x; 4.2999x over previous
//
#include <hip/hip_runtime.h>
#include <hip/hip_bf16.h>

// Problem constants: B=32, T=1024, D=512, K=3, L=max_len=4096.
#define BB 32
#define TT 1024
#define DD 512
#define LL 4096
#define KDIM 1536        // K*D (im2col reduction dim)
#define TP 1026          // padded T (+1 zero halo row each side)
#define ROWS (BB * TT)   // 32768
#define NT (KDIM / 32)   // 48 K-steps

typedef __attribute__((ext_vector_type(8))) short short8;
typedef __attribute__((ext_vector_type(8))) unsigned short ushort8;
typedef __attribute__((ext_vector_type(4))) float floatx4;

__device__ __forceinline__ unsigned short f2bf(float f) {
  unsigned int u = __builtin_bit_cast(unsigned int, f);
  u += 0x7FFF + ((u >> 16) & 1);
  return (unsigned short)(u >> 16);
}

#define GLOAD_LDS16(g, l)                                          \
  __builtin_amdgcn_global_load_lds(                                \
      (const __attribute__((address_space(1))) void*)(g),          \
      (__attribute__((address_space(3))) void*)(l), 16, 0, 0)

// ---------------------------------------------------------------------------
// Merged prep kernel (unchanged from round 9).
// ---------------------------------------------------------------------------
#define PAD_BLKS ((BB * TP) / 4)   // 8208
#define W0 (PAD_BLKS + 16)         // 8224
#define C0 (W0 + 384)              // 8608
#define PREP_BLKS (C0 + 32)        // 8640

__global__ __launch_bounds__(256) void prep_kernel(
    const float* __restrict__ X, unsigned short* __restrict__ Xp,
    unsigned short* __restrict__ Hp,
    const float* __restrict__ W1, unsigned short* __restrict__ Wt1,
    const float* __restrict__ W2, unsigned short* __restrict__ Wt2,
    const int* __restrict__ dur, int* __restrict__ cum,
    int* __restrict__ idx) {
  __shared__ float tile[64][65];
  const int tid = threadIdx.x;
  const int lane = tid & 63;

  if (blockIdx.x >= C0) {
    int* ls = reinterpret_cast<int*>(tile);
    const int b = blockIdx.x - C0;
    int4 v = reinterpret_cast<const int4*>(dur + b * TT)[tid];
    const int s0 = v.x, s1 = s0 + v.y, s2 = s1 + v.z, s3 = s2 + v.w;
    ls[tid] = s3;
    __syncthreads();
    for (int off = 1; off < 256; off <<= 1) {
      int x = (tid >= off) ? ls[tid - off] : 0;
      __syncthreads();
      ls[tid] += x;
      __syncthreads();
    }
    const int base = tid ? ls[tid - 1] : 0;
    int4 o = {base + s0, base + s1, base + s2, base + s3};
    reinterpret_cast<int4*>(cum + b * TT)[tid] = o;
    int* ib = idx + b * LL;
    int st = base;
    const int dv[4] = {v.x, v.y, v.z, v.w};
#pragma unroll
    for (int k = 0; k < 4; ++k) {
      const int e = min(st + dv[k], LL);
      for (int j = st; j < e; ++j) ib[j] = 4 * tid + k;
      st += dv[k];
    }
    return;
  }
  if (blockIdx.x >= W0) {
    const int w = blockIdx.x - W0;
    const int z = w / 192;
    const int rem = w - z * 192;
    const int bx = rem & 7;
    const int by = rem >> 3;
    const float* W = z ? W2 : W1;
    unsigned short* Wt = z ? Wt2 : Wt1;
    const int n0 = bx * 64;
    const int k0 = by * 64;
    const int c = lane;
    const int r4 = tid >> 6;
#pragma unroll
    for (int r = 0; r < 16; ++r)
      tile[r * 4 + r4][c] = W[(long)(k0 + r * 4 + r4) * DD + n0 + c];
    __syncthreads();
#pragma unroll
    for (int r = 0; r < 16; ++r)
      Wt[(long)(n0 + r * 4 + r4) * KDIM + k0 + c] = f2bf(tile[c][r * 4 + r4]);
    return;
  }
  if (blockIdx.x >= PAD_BLKS) {
    const int hid = (blockIdx.x - PAD_BLKS) * 4 + (tid >> 6);
    const int b = hid >> 1;
    const long r = (long)b * TP + ((hid & 1) ? (TP - 1) : 0);
    *reinterpret_cast<ushort8*>(Hp + r * DD + lane * 8) = (ushort8)0;
    return;
  }
  const int row = blockIdx.x * 4 + (tid >> 6);
  const int b  = row / TP;
  const int pr = row - b * TP;
  ushort8* o = reinterpret_cast<ushort8*>(Xp + (long)row * DD + lane * 8);
  ushort8 v;
  if (pr == 0 || pr == TP - 1) {
    v = (ushort8)0;
  } else {
    const float* p = X + ((long)(b * TT + pr - 1)) * DD + lane * 8;
    float4 a = *reinterpret_cast<const float4*>(p);
    float4 c = *reinterpret_cast<const float4*>(p + 4);
    v[0] = f2bf(a.x); v[1] = f2bf(a.y); v[2] = f2bf(a.z); v[3] = f2bf(a.w);
    v[4] = f2bf(c.x); v[5] = f2bf(c.y); v[6] = f2bf(c.z); v[7] = f2bf(c.w);
  }
  *o = v;
}

// ---------------------------------------------------------------------------
// Fused conv-as-GEMM + bias + ReLU + LayerNorm (+ linear head for LAYER==2).
// K-loop: round-9 form, byte-identical (16 waves 2Mx8N, acc[4][4], 3-buf,
// counted vmcnt(3)/(2)).
//
// ROUND-13 CHANGE (from round-12 ablation: K-loop=60us but production
// layer=85us -> LAYER1 epilogue = 25us, dominated by two serialized
// half-tile phases each ending in a syncthreads whose vmcnt(0) drains
// ~17MB of in-flight stores): SINGLE-PHASE epilogue. The K-loop LDS
// (As 24K + Bs 96K) is unioned with a full-tile staging buffer
// Ls[128][516] = 129 KB (block total 138 KB <= 160; still 1 block/CU,
// unchanged). All 16 waves write their LN'd rows once, one LDS barrier,
// then one coalesced 33.6 MB store pass with NO barrier after it (the
// dispatch boundary is the drain).
// ---------------------------------------------------------------------------
template <int LAYER>
__global__ __launch_bounds__(1024, 4) void fused_conv_ln_kernel(
    const unsigned short* __restrict__ Xp, const unsigned short* __restrict__ Wt,
    const float* __restrict__ bias, const float* __restrict__ g,
    const float* __restrict__ be, const float* __restrict__ lw,
    const float* __restrict__ lb, unsigned short* __restrict__ Hp,
    float* __restrict__ dpo) {
  // Union LDS: K-loop {As[3][4096], Bs[3][16384]} / epilogue Ls[128*516].
  __shared__ __align__(16) unsigned char smem[132096];  // 129 KB
  __shared__ float sS[8][128];
  __shared__ float sQ[8][128];
  __shared__ float muL[128];
  __shared__ float rsL[128];
  unsigned short* AsP = reinterpret_cast<unsigned short*>(smem);
  unsigned short* BsP = reinterpret_cast<unsigned short*>(smem + 24576);

  const int tid  = threadIdx.x;
  const int lane = tid & 63;
  const int wid  = tid >> 6;           // 0..15
  const int srow = lane >> 2;
  const int gchunk = (lane & 3) ^ (srow & 3) ^ ((srow >> 2) & 3);
  const int frow = lane & 15;
  const int quad = lane >> 4;
  const int rdch = quad ^ (frow & 3) ^ ((frow >> 2) & 3);
  const int wm = (wid >> 3) * 64;      // M-strip (2)
  const int wn = (wid & 7) * 64;       // N-slice (8)
  const int wc = wid & 7;

  const int m0 = blockIdx.x * 128;
  const int bA = m0 >> 10;
  const int t0 = m0 & (TT - 1);

  const unsigned short* gA0 =
      Xp + (long)(bA * TP + t0 + (wid & 7) * 16 + srow) * DD + gchunk * 8;
  const int bb0 = (wid < 8) ? wid * 32 : 256 + (wid - 8) * 32;
  const unsigned short* gB0 =
      Wt + (long)(bb0 + srow) * KDIM + gchunk * 8;

  floatx4 acc[4][4];
#pragma unroll
  for (int i = 0; i < 4; ++i)
#pragma unroll
    for (int j = 0; j < 4; ++j) acc[i][j] = (floatx4){0.f, 0.f, 0.f, 0.f};

#define STAGE(bi, kk)                                                         \
  do {                                                                        \
    const int tap_ = (kk) >> 9;                                               \
    const int c0_  = (kk) & 511;                                              \
    if (wid < 8)                                                              \
      GLOAD_LDS16(gA0 + (long)tap_ * DD + c0_,                                \
                  &AsP[(bi) * 4096 + (wid * 16) * 32]);                       \
    GLOAD_LDS16(gB0 + (kk), &BsP[(bi) * 16384 + bb0 * 32]);                   \
    GLOAD_LDS16(gB0 + (long)16 * KDIM + (kk),                                 \
                &BsP[(bi) * 16384 + (bb0 + 16) * 32]);                        \
  } while (0)

#define COMPUTE(bi)                                                           \
  do {                                                                        \
    short8 a_[4], b_[4];                                                      \
    _Pragma("unroll")                                                         \
    for (int i = 0; i < 4; ++i)                                               \
      a_[i] = *reinterpret_cast<const short8*>(                               \
          &AsP[(bi) * 4096 + (wm + i * 16 + frow) * 32 + rdch * 8]);          \
    _Pragma("unroll")                                                         \
    for (int j = 0; j < 4; ++j)                                               \
      b_[j] = *reinterpret_cast<const short8*>(                               \
          &BsP[(bi) * 16384 + (wn + j * 16 + frow) * 32 + rdch * 8]);         \
    _Pragma("unroll")                                                         \
    for (int i = 0; i < 4; ++i)                                               \
      _Pragma("unroll")                                                       \
      for (int j = 0; j < 4; ++j)                                             \
        acc[i][j] = __builtin_amdgcn_mfma_f32_16x16x32_bf16(                  \
            a_[i], b_[j], acc[i][j], 0, 0, 0);                                \
  } while (0)

  STAGE(0, 0);
  STAGE(1, 32);

  int cur = 0;
  int stg = 2;
  for (int t = 0; t < NT - 1; ++t) {
    if (wid < 8) asm volatile("s_waitcnt vmcnt(3)" ::: "memory");
    else         asm volatile("s_waitcnt vmcnt(2)" ::: "memory");
    __builtin_amdgcn_s_barrier();
    __builtin_amdgcn_sched_barrier(0);
    if (t + 2 < NT) STAGE(stg, (t + 2) * 32);
    COMPUTE(cur);
    cur = (cur == 2) ? 0 : cur + 1;
    stg = (stg == 2) ? 0 : stg + 1;
  }
  asm volatile("s_waitcnt vmcnt(0)" ::: "memory");
  __builtin_amdgcn_s_barrier();
  __builtin_amdgcn_sched_barrier(0);
  COMPUTE(cur);
#undef STAGE
#undef COMPUTE

  // --- bias + relu in place ---
  float bz[4];
#pragma unroll
  for (int j = 0; j < 4; ++j) bz[j] = bias[wn + j * 16 + frow];
#pragma unroll
  for (int i = 0; i < 4; ++i)
#pragma unroll
    for (int j = 0; j < 4; ++j)
#pragma unroll
      for (int r = 0; r < 4; ++r)
        acc[i][j][r] = fmaxf(acc[i][j][r] + bz[j], 0.f);

  // --- per-row LN stats ---
  float ps[16], pq[16];
#pragma unroll
  for (int i = 0; i < 4; ++i)
#pragma unroll
    for (int r = 0; r < 4; ++r) {
      float s = 0.f, q = 0.f;
#pragma unroll
      for (int j = 0; j < 4; ++j) {
        const float v = acc[i][j][r];
        s += v; q += v * v;
      }
      ps[i * 4 + r] = s; pq[i * 4 + r] = q;
    }
#pragma unroll
  for (int off = 1; off < 16; off <<= 1)
#pragma unroll
    for (int k = 0; k < 16; ++k) {
      ps[k] += __shfl_xor(ps[k], off);
      pq[k] += __shfl_xor(pq[k], off);
    }
  if (frow == 0) {
#pragma unroll
    for (int i = 0; i < 4; ++i)
#pragma unroll
      for (int r = 0; r < 4; ++r) {
        const int row = wm + i * 16 + quad * 4 + r;
        sS[wc][row] = ps[i * 4 + r];
        sQ[wc][row] = pq[i * 4 + r];
      }
  }
  __syncthreads();
  if (tid < 128) {
    float s = 0.f, q = 0.f;
#pragma unroll
    for (int c = 0; c < 8; ++c) { s += sS[c][tid]; q += sQ[c][tid]; }
    const float mu = s * (1.f / DD);
    const float var = q * (1.f / DD) - mu * mu;
    muL[tid] = mu;
    rsL[tid] = rsqrtf(var + 1e-5f);
  }
  __syncthreads();  // muL/rsL ready; K-loop LDS dead -> smem reusable as Ls

  float gg[4], bb[4];
#pragma unroll
  for (int j = 0; j < 4; ++j) {
    gg[j] = g[wn + j * 16 + frow];
    bb[j] = be[wn + j * 16 + frow];
  }

  if constexpr (LAYER == 1) {
    // SINGLE-PHASE: all waves LN->bf16 into Ls[128][516] (129 KB union),
    // one LDS barrier, one coalesced store pass, no trailing barrier.
    unsigned short* Ls = reinterpret_cast<unsigned short*>(smem);
#pragma unroll
    for (int i = 0; i < 4; ++i)
#pragma unroll
      for (int r = 0; r < 4; ++r) {
        const int row = wm + i * 16 + quad * 4 + r;
        const float mu = muL[row];
        const float rs = rsL[row];
        const int base = row * 516 + wn;
#pragma unroll
        for (int j = 0; j < 4; ++j) {
          const float v = (acc[i][j][r] - mu) * rs * gg[j] + bb[j];
          Ls[base + j * 16 + frow] = f2bf(v);
        }
      }
    __syncthreads();
    const long gbase = (long)(bA * TP + t0 + 1) * DD;
#pragma unroll
    for (int it = 0; it < 8; ++it) {
      const int r2 = it * 16 + wid;
      ushort8 val = *reinterpret_cast<const ushort8*>(&Ls[r2 * 516 + lane * 8]);
      *reinterpret_cast<ushort8*>(&Hp[gbase + (long)r2 * DD + lane * 8]) = val;
    }
  } else {
    // LN -> dot with lin_w -> dpo (unchanged).
    float ww[4];
#pragma unroll
    for (int j = 0; j < 4; ++j) ww[j] = lw[wn + j * 16 + frow];
#pragma unroll
    for (int i = 0; i < 4; ++i)
#pragma unroll
      for (int r = 0; r < 4; ++r) {
        const int row = wm + i * 16 + quad * 4 + r;
        const float mu = muL[row];
        const float rs = rsL[row];
        float d = 0.f;
#pragma unroll
        for (int j = 0; j < 4; ++j) {
          const float v = (acc[i][j][r] - mu) * rs * gg[j] + bb[j];
          d += v * ww[j];
        }
#pragma unroll
        for (int off = 1; off < 16; off <<= 1) d += __shfl_xor(d, off);
        if (frow == 0) sS[wc][row] = d;
      }
    __syncthreads();
    if (tid < 128) {
      float s = lb[0];
#pragma unroll
      for (int c = 0; c < 8; ++c) s += sS[c][tid];
      dpo[blockIdx.x * 128 + tid] = s;
    }
  }
}

// ---------------------------------------------------------------------------
// Gather/expand (round-9 form).
// ---------------------------------------------------------------------------
__global__ __launch_bounds__(512) void gather_kernel(
    const float* __restrict__ X, const int* __restrict__ cum,
    const int* __restrict__ idx, float* __restrict__ out) {
  const long gf = (long)blockIdx.x * 4 + (threadIdx.x >> 7);
  const int tl = threadIdx.x & 127;
  const int b = (int)(gf >> 12);
  const int j = (int)(gf & (LL - 1));
  const int total = cum[b * TT + TT - 1];
  floatx4* o = reinterpret_cast<floatx4*>(out + gf * DD) + tl;
  if (j >= total) {
    *o = (floatx4){0.f, 0.f, 0.f, 0.f};
    return;
  }
  const int lo = idx[b * LL + j];
  const floatx4* src =
      reinterpret_cast<const floatx4*>(X + ((long)b * TT + lo) * DD) + tl;
  *o = *src;
}

// ---------------------------------------------------------------------------
extern "C" void kernel_launch(void* const* d_in, const int* in_sizes, int n_in,
                              void* d_out, int out_size, void* d_ws,
                              size_t ws_size, hipStream_t stream) {
  const float* enc = (const float*)d_in[0];
  const int* dur   = (const int*)d_in[1];
  const float* w1  = (const float*)d_in[2];
  const float* b1  = (const float*)d_in[3];
  const float* g1  = (const float*)d_in[4];
  const float* be1 = (const float*)d_in[5];
  const float* w2  = (const float*)d_in[6];
  const float* b2  = (const float*)d_in[7];
  const float* g2  = (const float*)d_in[8];
  const float* be2 = (const float*)d_in[9];
  const float* lw  = (const float*)d_in[10];
  const float* lb  = (const float*)d_in[11];

  float* out = (float*)d_out;
  float* expanded = out;                       // [B, L, D] = 67,108,864 f
  float* dpo = out + (long)BB * LL * DD;       // [B, T]

  // Scratch carved out of the 256 MB expanded region (gather writes it last).
  unsigned short* enc_pad = (unsigned short*)(expanded);              // 33.6 MB
  unsigned short* h1_pad  = (unsigned short*)(expanded + 9000000);    // 33.6 MB
  unsigned short* wt1     = (unsigned short*)(expanded + 18000000);   // 1.5 MB
  unsigned short* wt2     = (unsigned short*)(expanded + 18400000);   // 1.5 MB
  int* cum = (int*)d_ws;                        // 32768 ints
  int* idx = (int*)d_ws + ROWS;                 // 131072 ints

  prep_kernel<<<PREP_BLKS, 256, 0, stream>>>(enc, enc_pad, h1_pad, w1, wt1,
                                             w2, wt2, dur, cum, idx);

  fused_conv_ln_kernel<1><<<ROWS / 128, 1024, 0, stream>>>(
      enc_pad, wt1, b1, g1, be1, nullptr, nullptr, h1_pad, nullptr);
  fused_conv_ln_kernel<2><<<ROWS / 128, 1024, 0, stream>>>(
      h1_pad, wt2, b2, g2, be2, lw, lb, nullptr, dpo);

  gather_kernel<<<BB * LL / 4, 512, 0, stream>>>(enc, cum, idx, expanded);
}